// Round 1
// baseline (4275.212 us; speedup 1.0000x reference)
//
#include <hip/hip_runtime.h>

#define EPS 1e-5f

__device__ __forceinline__ float wave_sum(float v) {
  #pragma unroll
  for (int o = 32; o > 0; o >>= 1) v += __shfl_down(v, o, 64);
  return v;
}

// ---- degree count (before +1 self loop) ----
__global__ void k_deg(const int* __restrict__ dst, int E, int* __restrict__ cnt) {
  int i = blockIdx.x * blockDim.x + threadIdx.x;
  if (i < E) atomicAdd(&cnt[dst[i]], 1);
}

// ---- bn0 stats: sum, sumsq of x ----
__global__ void k_s0(const float* __restrict__ x, int N, float* __restrict__ sums) {
  float s = 0.f, q = 0.f;
  for (int i = blockIdx.x * blockDim.x + threadIdx.x; i < N; i += gridDim.x * blockDim.x) {
    float v = x[i];
    s += v;
    q = fmaf(v, v, q);
  }
  s = wave_sum(s);
  q = wave_sum(q);
  if ((threadIdx.x & 63) == 0) { atomicAdd(&sums[0], s); atomicAdd(&sums[1], q); }
}

// ---- bn0 affine: h0 = x*ab[0] + ab[1] ----
__global__ void k_c0(const float* __restrict__ sums, const float* __restrict__ g,
                     const float* __restrict__ b, float invN, float* __restrict__ ab) {
  float mu = sums[0] * invN;
  float var = fmaf(-mu, mu, sums[1] * invN);
  float r = rsqrtf(var + EPS);
  float a = g[0] * r;
  ab[0] = a;
  ab[1] = b[0] - mu * a;
}

// ---- dinv = rsqrt(deg+1); agg1 init with self-loop term of h0 ----
__global__ void k_dinv_init(const int* __restrict__ cnt, const float* __restrict__ x,
                            const float* __restrict__ ab0, int N,
                            float* __restrict__ dinv, float* __restrict__ agg1) {
  int i = blockIdx.x * blockDim.x + threadIdx.x;
  if (i >= N) return;
  float dv = rsqrtf((float)cnt[i] + 1.0f);
  dinv[i] = dv;
  float h0 = fmaf(x[i], ab0[0], ab0[1]);
  agg1[i] = h0 * dv * dv;
}

// ---- layer-1 edge aggregation (F_in = 1), h0 computed on the fly ----
__global__ void k_a1(const int* __restrict__ src, const int* __restrict__ dst, int E,
                     const float* __restrict__ x, const float* __restrict__ dinv,
                     const float* __restrict__ ab0, float* __restrict__ agg1) {
  int e = blockIdx.x * blockDim.x + threadIdx.x;
  if (e >= E) return;
  int s = src[e], d = dst[e];
  float c = dinv[s] * dinv[d];
  float h0 = fmaf(x[s], ab0[0], ab0[1]);
  atomicAdd(&agg1[d], c * h0);
}

// ---- generic edge aggregation: thread = (edge, channel) ----
template<int F>
__global__ void k_agg(const int* __restrict__ src, const int* __restrict__ dst, int EF,
                      const float* __restrict__ h, const float* __restrict__ dinv,
                      float* __restrict__ agg) {
  int idx = blockIdx.x * blockDim.x + threadIdx.x;
  if (idx >= EF) return;
  constexpr int SH = (F == 8) ? 3 : 4;
  int e = idx >> SH;
  int j = idx & (F - 1);
  int s = src[e], d = dst[e];
  float c = dinv[s] * dinv[d];
  atomicAdd(&agg[d * F + j], c * h[s * F + j]);
}

// ---- per-channel stats of y = gW + b (recompute y, accumulate sums) ----
template<int FI, int FO>
__global__ void k_stats(const float* __restrict__ g, const float* __restrict__ W,
                        const float* __restrict__ b, int N, float* __restrict__ sums) {
  __shared__ float Ws[FI * FO];
  __shared__ float bs[FO];
  for (int t = threadIdx.x; t < FI * FO; t += blockDim.x) Ws[t] = W[t];
  for (int t = threadIdx.x; t < FO; t += blockDim.x) bs[t] = b[t];
  __syncthreads();

  float s[FO], q[FO];
  #pragma unroll
  for (int j = 0; j < FO; j++) { s[j] = 0.f; q[j] = 0.f; }

  for (int i = blockIdx.x * blockDim.x + threadIdx.x; i < N; i += gridDim.x * blockDim.x) {
    float gv[FI];
    if constexpr (FI % 4 == 0) {
      const float4* g4 = (const float4*)(g + (size_t)i * FI);
      #pragma unroll
      for (int k = 0; k < FI / 4; k++) {
        float4 v = g4[k];
        gv[4 * k] = v.x; gv[4 * k + 1] = v.y; gv[4 * k + 2] = v.z; gv[4 * k + 3] = v.w;
      }
    } else {
      #pragma unroll
      for (int k = 0; k < FI; k++) gv[k] = g[(size_t)i * FI + k];
    }
    #pragma unroll
    for (int j = 0; j < FO; j++) {
      float y = bs[j];
      #pragma unroll
      for (int k = 0; k < FI; k++) y = fmaf(gv[k], Ws[k * FO + j], y);
      s[j] += y;
      q[j] = fmaf(y, y, q[j]);
    }
  }
  #pragma unroll
  for (int j = 0; j < FO; j++) {
    float sv = wave_sum(s[j]);
    float qv = wave_sum(q[j]);
    if ((threadIdx.x & 63) == 0) {
      atomicAdd(&sums[j], sv);
      atomicAdd(&sums[FO + j], qv);
    }
  }
}

// ---- fold BN into per-channel affine ----
template<int FO>
__global__ void k_affine(const float* __restrict__ sums, const float* __restrict__ gamma,
                         const float* __restrict__ beta, float invN, float* __restrict__ ab) {
  int j = threadIdx.x;
  if (j >= FO) return;
  float mu = sums[j] * invN;
  float var = fmaf(-mu, mu, sums[FO + j] * invN);
  float r = rsqrtf(var + EPS);
  float a = gamma[j] * r;
  ab[j] = a;
  ab[FO + j] = beta[j] - mu * a;
}

// ---- transform: h = relu((gW+b)*alpha+delta); also init next agg with h*dinv^2 ----
template<int FI, int FO>
__global__ void k_transform(const float* __restrict__ g, const float* __restrict__ W,
                            const float* __restrict__ b, const float* __restrict__ ab,
                            const float* __restrict__ dinv, int N,
                            float* __restrict__ h, float* __restrict__ aggn) {
  __shared__ float Ws[FI * FO];
  __shared__ float bs[FO];
  __shared__ float as2[2 * FO];
  for (int t = threadIdx.x; t < FI * FO; t += blockDim.x) Ws[t] = W[t];
  for (int t = threadIdx.x; t < FO; t += blockDim.x) bs[t] = b[t];
  for (int t = threadIdx.x; t < 2 * FO; t += blockDim.x) as2[t] = ab[t];
  __syncthreads();

  int i = blockIdx.x * blockDim.x + threadIdx.x;
  if (i >= N) return;

  float gv[FI];
  if constexpr (FI % 4 == 0) {
    const float4* g4 = (const float4*)(g + (size_t)i * FI);
    #pragma unroll
    for (int k = 0; k < FI / 4; k++) {
      float4 v = g4[k];
      gv[4 * k] = v.x; gv[4 * k + 1] = v.y; gv[4 * k + 2] = v.z; gv[4 * k + 3] = v.w;
    }
  } else {
    #pragma unroll
    for (int k = 0; k < FI; k++) gv[k] = g[(size_t)i * FI + k];
  }

  float dv = dinv[i];
  float dv2 = dv * dv;
  float hv[FO];
  #pragma unroll
  for (int j = 0; j < FO; j++) {
    float y = bs[j];
    #pragma unroll
    for (int k = 0; k < FI; k++) y = fmaf(gv[k], Ws[k * FO + j], y);
    hv[j] = fmaxf(fmaf(y, as2[j], as2[FO + j]), 0.f);
  }
  float4* h4 = (float4*)(h + (size_t)i * FO);
  float4* a4 = (float4*)(aggn + (size_t)i * FO);
  #pragma unroll
  for (int k = 0; k < FO / 4; k++) {
    float4 t;
    t.x = hv[4 * k]; t.y = hv[4 * k + 1]; t.z = hv[4 * k + 2]; t.w = hv[4 * k + 3];
    h4[k] = t;
    float4 u;
    u.x = t.x * dv2; u.y = t.y * dv2; u.z = t.z * dv2; u.w = t.w * dv2;
    a4[k] = u;
  }
}

// ---- layer-3 transform fused with segment-max pooling ----
template<int FI, int FO>
__global__ void k_pool(const float* __restrict__ g, const float* __restrict__ W,
                       const float* __restrict__ b, const float* __restrict__ ab,
                       const int* __restrict__ batch, int N, int B,
                       unsigned* __restrict__ pooled) {
  __shared__ float Ws[FI * FO];
  __shared__ float bs[FO];
  __shared__ float as2[2 * FO];
  __shared__ unsigned lpool[4 * FO];
  __shared__ int gid0s;
  for (int t = threadIdx.x; t < FI * FO; t += blockDim.x) Ws[t] = W[t];
  for (int t = threadIdx.x; t < FO; t += blockDim.x) bs[t] = b[t];
  for (int t = threadIdx.x; t < 2 * FO; t += blockDim.x) as2[t] = ab[t];
  if (threadIdx.x < 4 * FO) lpool[threadIdx.x] = 0u;
  int i0 = blockIdx.x * blockDim.x;
  if (threadIdx.x == 0) gid0s = batch[i0 < N ? i0 : (N - 1)];
  __syncthreads();
  int gid0 = gid0s;

  int i = i0 + threadIdx.x;
  if (i < N) {
    float gv[FI];
    const float4* g4 = (const float4*)(g + (size_t)i * FI);
    #pragma unroll
    for (int k = 0; k < FI / 4; k++) {
      float4 v = g4[k];
      gv[4 * k] = v.x; gv[4 * k + 1] = v.y; gv[4 * k + 2] = v.z; gv[4 * k + 3] = v.w;
    }
    int gid = batch[i];
    int slot = gid - gid0;
    #pragma unroll
    for (int j = 0; j < FO; j++) {
      float y = bs[j];
      #pragma unroll
      for (int k = 0; k < FI; k++) y = fmaf(gv[k], Ws[k * FO + j], y);
      float hv = fmaxf(fmaf(y, as2[j], as2[FO + j]), 0.f);
      unsigned u = __float_as_uint(hv);
      if (slot >= 0 && slot < 4) atomicMax(&lpool[slot * FO + j], u);
      else atomicMax(&pooled[(size_t)gid * FO + j], u);
    }
  }
  __syncthreads();
  for (int t = threadIdx.x; t < 4 * FO; t += blockDim.x) {
    unsigned v = lpool[t];
    int gid = gid0 + t / FO;
    if (v && gid < B) atomicMax(&pooled[(size_t)gid * FO + (t % FO)], v);
  }
}

// ---- final MLP: relu(relu(p@L1W+L1b)@L2W+L2b) ----
__global__ void k_mlp(const unsigned* __restrict__ pooled, const float* __restrict__ W1,
                      const float* __restrict__ b1, const float* __restrict__ W2,
                      const float* __restrict__ b2, int B, float* __restrict__ out) {
  int gidx = blockIdx.x * blockDim.x + threadIdx.x;
  if (gidx >= B) return;
  float p[32];
  #pragma unroll
  for (int k = 0; k < 32; k++) p[k] = __uint_as_float(pooled[gidx * 32 + k]);
  float o0 = b2[0], o1 = b2[1];
  for (int j = 0; j < 64; j++) {
    float y = b1[j];
    #pragma unroll
    for (int k = 0; k < 32; k++) y = fmaf(p[k], W1[k * 64 + j], y);
    y = fmaxf(y, 0.f);
    o0 = fmaf(y, W2[j * 2 + 0], o0);
    o1 = fmaf(y, W2[j * 2 + 1], o1);
  }
  out[gidx * 2 + 0] = fmaxf(o0, 0.f);
  out[gidx * 2 + 1] = fmaxf(o1, 0.f);
}

extern "C" void kernel_launch(void* const* d_in, const int* in_sizes, int n_in,
                              void* d_out, int out_size, void* d_ws, size_t ws_size,
                              hipStream_t stream) {
  const float* x     = (const float*)d_in[0];
  const int*   ei    = (const int*)d_in[1];
  const int*   batch = (const int*)d_in[2];
  const float* bn0_g = (const float*)d_in[3];
  const float* bn0_b = (const float*)d_in[4];
  const float* W1    = (const float*)d_in[5];
  const float* b1    = (const float*)d_in[6];
  const float* bn1_g = (const float*)d_in[7];
  const float* bn1_b = (const float*)d_in[8];
  const float* W2    = (const float*)d_in[9];
  const float* b2    = (const float*)d_in[10];
  const float* bn2_g = (const float*)d_in[11];
  const float* bn2_b = (const float*)d_in[12];
  const float* W3    = (const float*)d_in[13];
  const float* b3    = (const float*)d_in[14];
  const float* bn3_g = (const float*)d_in[15];
  const float* bn3_b = (const float*)d_in[16];
  const float* L1W   = (const float*)d_in[17];
  const float* L1b   = (const float*)d_in[18];
  const float* L2W   = (const float*)d_in[19];
  const float* L2b   = (const float*)d_in[20];

  const int N = in_sizes[0];
  const int E = in_sizes[1] / 2;
  const int B = out_size / 2;
  const int* src = ei;
  const int* dst = ei + E;
  const float invN = 1.0f / (float)N;

  char* ws = (char*)d_ws;
  size_t off = 0;
  auto alloc = [&](size_t bytes) {
    char* p = ws + off;
    off += (bytes + 255) & ~(size_t)255;
    return p;
  };
  int*      cnt    = (int*)alloc((size_t)N * 4);
  float*    dinv   = (float*)alloc((size_t)N * 4);
  float*    agg1   = (float*)alloc((size_t)N * 4);
  float*    h1     = (float*)alloc((size_t)N * 8 * 4);
  float*    agg2   = (float*)alloc((size_t)N * 8 * 4);
  float*    h2     = (float*)alloc((size_t)N * 16 * 4);
  float*    agg3   = (float*)alloc((size_t)N * 16 * 4);
  unsigned* pooled = (unsigned*)alloc((size_t)B * 32 * 4);
  float*    stats  = (float*)alloc(1024 * 4);

  float* sums0 = stats + 0;    // 2
  float* ab0   = stats + 4;    // 2
  float* sums1 = stats + 8;    // 16
  float* ab1   = stats + 24;   // 16
  float* sums2 = stats + 40;   // 32
  float* ab2   = stats + 72;   // 32
  float* sums3 = stats + 104;  // 64
  float* ab3   = stats + 168;  // 64

  hipMemsetAsync(cnt, 0, (size_t)N * 4, stream);
  hipMemsetAsync(stats, 0, 1024 * 4, stream);
  hipMemsetAsync(pooled, 0, (size_t)B * 32 * 4, stream);

  const int T = 256;
  const int gN = (N + T - 1) / T;
  const int gE = (E + T - 1) / T;
  const int gS = 1024;  // grid-stride stats kernels

  k_deg<<<gE, T, 0, stream>>>(dst, E, cnt);
  k_s0<<<gS, T, 0, stream>>>(x, N, sums0);
  k_c0<<<1, 1, 0, stream>>>(sums0, bn0_g, bn0_b, invN, ab0);
  k_dinv_init<<<gN, T, 0, stream>>>(cnt, x, ab0, N, dinv, agg1);

  // layer 1
  k_a1<<<gE, T, 0, stream>>>(src, dst, E, x, dinv, ab0, agg1);
  k_stats<1, 8><<<gS, T, 0, stream>>>(agg1, W1, b1, N, sums1);
  k_affine<8><<<1, 64, 0, stream>>>(sums1, bn1_g, bn1_b, invN, ab1);
  k_transform<1, 8><<<gN, T, 0, stream>>>(agg1, W1, b1, ab1, dinv, N, h1, agg2);

  // layer 2
  {
    int EF = E * 8;
    k_agg<8><<<(EF + T - 1) / T, T, 0, stream>>>(src, dst, EF, h1, dinv, agg2);
  }
  k_stats<8, 16><<<gS, T, 0, stream>>>(agg2, W2, b2, N, sums2);
  k_affine<16><<<1, 64, 0, stream>>>(sums2, bn2_g, bn2_b, invN, ab2);
  k_transform<8, 16><<<gN, T, 0, stream>>>(agg2, W2, b2, ab2, dinv, N, h2, agg3);

  // layer 3
  {
    int EF = E * 16;
    k_agg<16><<<(EF + T - 1) / T, T, 0, stream>>>(src, dst, EF, h2, dinv, agg3);
  }
  k_stats<16, 32><<<gS, T, 0, stream>>>(agg3, W3, b3, N, sums3);
  k_affine<32><<<1, 64, 0, stream>>>(sums3, bn3_g, bn3_b, invN, ab3);
  k_pool<16, 32><<<gN, T, 0, stream>>>(agg3, W3, b3, ab3, batch, N, B, pooled);

  // final MLP
  k_mlp<<<(B + T - 1) / T, T, 0, stream>>>(pooled, L1W, L1b, L2W, L2b, B, (float*)d_out);
}